// Round 1
// baseline (783.150 us; speedup 1.0000x reference)
//
#include <hip/hip_runtime.h>

typedef __bf16 bf16_t;
typedef __bf16 bf16x8 __attribute__((ext_vector_type(8)));
typedef __bf16 bf16x4 __attribute__((ext_vector_type(4)));
typedef float  f32x4  __attribute__((ext_vector_type(4)));
typedef float  f32x8  __attribute__((ext_vector_type(8)));

#define MFMA16(a, b, c) __builtin_amdgcn_mfma_f32_16x16x32_bf16((a), (b), (c), 0, 0, 0)

// LDS layout (bf16 elements). Strides chosen so every b128 fragment read is
// 16B-aligned and row-stride mod 32 dwords == 4 (2-way bank alias only, free).
#define QK_STRIDE  392   // [64][392]: q cols 0..191, k cols 192..383, pad
#define VT_STRIDE  72    // [192][72]: vT[dim][token]
#define XA_STRIDE  200   // [64][200]: x, later attn_out
#define P_STRIDE   72    // per-wave [64][72]
#define QK_ELEMS   (64 * QK_STRIDE)     // 25088
#define VT_ELEMS   (192 * VT_STRIDE)    // 13824
#define XA_ELEMS   (64 * XA_STRIDE)     // 12800
#define P_ELEMS    (64 * P_STRIDE)      // 4608 per wave
#define SMEM_ELEMS (QK_ELEMS + VT_ELEMS + XA_ELEMS + 6 * P_ELEMS + 1014) // 80374 -> 160748 B

__device__ __forceinline__ bf16x8 load_w8_bf16(const float* __restrict__ p) {
    // 8 fp32 -> bf16x8 (two dwordx4 loads + pack); B-fragment from row-major weights
    f32x8 v;
    const float4 a = *(const float4*)p;
    const float4 b = *(const float4*)(p + 4);
    v[0] = a.x; v[1] = a.y; v[2] = a.z; v[3] = a.w;
    v[4] = b.x; v[5] = b.y; v[6] = b.z; v[7] = b.w;
    return __builtin_convertvector(v, bf16x8);
}

__global__ __launch_bounds__(384, 1)
void swin_fused_kernel(const float* __restrict__ x,
                       const float* __restrict__ qkv_w,
                       const float* __restrict__ qkv_b,
                       const float* __restrict__ proj_w,
                       const float* __restrict__ proj_b,
                       const float* __restrict__ tbl,
                       float* __restrict__ out)
{
    __shared__ __align__(16) bf16_t smem[SMEM_ELEMS];
    bf16_t* qk  = smem;                 // q,k row-major [token][col]
    bf16_t* vT  = qk  + QK_ELEMS;       // v transposed [dim][token]
    bf16_t* xao = vT  + VT_ELEMS;       // x (phase1), attn_out (phase2/3)
    bf16_t* Pb  = xao + XA_ELEMS;       // per-wave P
    bf16_t* bt  = Pb  + 6 * P_ELEMS;    // rel bias table [169][6]

    const int tid    = threadIdx.x;
    const int lane   = tid & 63;
    const int wave   = tid >> 6;        // 0..5 == head
    const int lanelo = lane & 15;
    const int quad   = lane >> 4;

    const int blk = blockIdx.x;
    const int b   = blk >> 8;
    const int wh  = (blk >> 4) & 15;
    const int ww  = blk & 15;
    const int rowbase = wh * 7 + 3;     // shift roll: shifted (i) -> orig (i+3)%112
    const int colbase = ww * 7 + 3;

    // ---- phase 0: bias table + x window -> LDS bf16 (rows 49..63 zeroed) ----
    for (int i = tid; i < 1014; i += 384) bt[i] = (bf16_t)tbl[i];

    for (int idx = tid; idx < 64 * 48; idx += 384) {
        const int t  = idx / 48;
        const int c4 = (idx - t * 48) * 4;
        bf16x4 v4;
        if (t < 49) {
            int gr = rowbase + t / 7;  if (gr >= 112) gr -= 112;
            int gc = colbase + t % 7;  if (gc >= 112) gc -= 112;
            const float4 f = *(const float4*)(x + (((long)b * 112 + gr) * 112 + gc) * 192 + c4);
            v4[0] = (bf16_t)f.x; v4[1] = (bf16_t)f.y;
            v4[2] = (bf16_t)f.z; v4[3] = (bf16_t)f.w;
        } else {
            v4[0] = (bf16_t)0.0f; v4[1] = (bf16_t)0.0f;
            v4[2] = (bf16_t)0.0f; v4[3] = (bf16_t)0.0f;
        }
        *(bf16x4*)(xao + t * XA_STRIDE + c4) = v4;
    }
    __syncthreads();

    // ---- phase 1: qkv = x @ qkv_w^T + qkv_b ; q,k -> qk LDS, v -> vT LDS ----
    {
        for (int ntl = 0; ntl < 6; ++ntl) {
            const int nt = wave * 6 + ntl;       // 36 N-tiles over 6 waves
            const int o  = nt * 16 + lanelo;     // output column (0..575)
            f32x4 acc[4] = {};
            #pragma unroll
            for (int ks = 0; ks < 6; ++ks) {
                const bf16x8 bfr = load_w8_bf16(qkv_w + o * 192 + ks * 32 + quad * 8);
                #pragma unroll
                for (int mi = 0; mi < 4; ++mi) {
                    const bf16x8 afr = *(const bf16x8*)(xao + (mi * 16 + lanelo) * XA_STRIDE + ks * 32 + quad * 8);
                    acc[mi] = MFMA16(afr, bfr, acc[mi]);
                }
            }
            const float bias = qkv_b[o];
            #pragma unroll
            for (int mi = 0; mi < 4; ++mi) {
                #pragma unroll
                for (int r = 0; r < 4; ++r) {
                    const int row = mi * 16 + quad * 4 + r;   // token (incl. pad rows -> finite bias)
                    const float v = acc[mi][r] + bias;
                    if (o < 384) qk[row * QK_STRIDE + o] = (bf16_t)v;       // q or k
                    else         vT[(o - 384) * VT_STRIDE + row] = (bf16_t)v; // v transposed
                }
            }
        }
    }
    __syncthreads();

    // ---- phase 2: per-head attention (wave == head) ----
    {
        const int h = wave;
        const float scale = 0.17677669529663687f;   // 32^-0.5
        bf16_t* Pme = Pb + wave * P_ELEMS;

        bf16x8 qa[4], kb[4];
        #pragma unroll
        for (int i = 0; i < 4; ++i) {
            qa[i] = *(const bf16x8*)(qk + (i * 16 + lanelo) * QK_STRIDE + h * 32 + quad * 8);
            kb[i] = *(const bf16x8*)(qk + (i * 16 + lanelo) * QK_STRIDE + 192 + h * 32 + quad * 8);
        }
        f32x4 s[4][4];
        #pragma unroll
        for (int mi = 0; mi < 4; ++mi)
            #pragma unroll
            for (int ni = 0; ni < 4; ++ni) {
                f32x4 z = {0.f, 0.f, 0.f, 0.f};
                s[mi][ni] = MFMA16(qa[mi], kb[ni], z);
            }

        // per-lane column (key) attributes for each ni tile
        int kvalid[4], kch[4], kcw[4], kid[4];
        #pragma unroll
        for (int ni = 0; ni < 4; ++ni) {
            const int col = ni * 16 + lanelo;
            kvalid[ni] = (col < 49);
            const int cc = kvalid[ni] ? col : 48;
            kch[ni] = cc / 7; kcw[ni] = cc - kch[ni] * 7;
            const int gr = wh * 7 + kch[ni], gc = ww * 7 + kcw[ni];
            kid[ni] = (gr < 105 ? 0 : (gr < 109 ? 1 : 2)) * 3 + (gc < 105 ? 0 : (gc < 109 ? 1 : 2));
        }

        #pragma unroll
        for (int mi = 0; mi < 4; ++mi) {
            #pragma unroll
            for (int r = 0; r < 4; ++r) {
                const int row = mi * 16 + quad * 4 + r;
                const int rq  = (row < 49) ? row : 48;       // clamp pad-query rows
                const int rh  = rq / 7, rw = rq - (rq / 7) * 7;
                const int gqr = wh * 7 + rh, gqc = ww * 7 + rw;
                const int idq = (gqr < 105 ? 0 : (gqr < 109 ? 1 : 2)) * 3 + (gqc < 105 ? 0 : (gqc < 109 ? 1 : 2));
                // bias + mask elementwise
                #pragma unroll
                for (int ni = 0; ni < 4; ++ni) {
                    float v;
                    if (kvalid[ni]) {
                        const int bidx = ((rh - kch[ni] + 6) * 13 + (rw - kcw[ni] + 6)) * 6 + h;
                        v = s[mi][ni][r] * scale + (float)bt[bidx];
                        if (idq != kid[ni]) v -= 100.0f;
                    } else {
                        v = -1e30f;
                    }
                    s[mi][ni][r] = v;
                }
                // row max over the 16-lane group holding this row
                float m0 = fmaxf(fmaxf(s[mi][0][r], s[mi][1][r]), fmaxf(s[mi][2][r], s[mi][3][r]));
                m0 = fmaxf(m0, __shfl_xor(m0, 1));
                m0 = fmaxf(m0, __shfl_xor(m0, 2));
                m0 = fmaxf(m0, __shfl_xor(m0, 4));
                m0 = fmaxf(m0, __shfl_xor(m0, 8));
                float sum = 0.f;
                #pragma unroll
                for (int ni = 0; ni < 4; ++ni) {
                    const float e = __expf(s[mi][ni][r] - m0);
                    s[mi][ni][r] = e;
                    sum += e;
                }
                sum += __shfl_xor(sum, 1);
                sum += __shfl_xor(sum, 2);
                sum += __shfl_xor(sum, 4);
                sum += __shfl_xor(sum, 8);
                const float rinv = 1.0f / sum;   // sum >= 1 always (exp(0) at argmax)
                #pragma unroll
                for (int ni = 0; ni < 4; ++ni)
                    Pme[row * P_STRIDE + ni * 16 + lanelo] = (bf16_t)(s[mi][ni][r] * rinv);
            }
        }

        // PV: out_h = P @ v   (A from Pme, B from vT — contiguous b128 reads)
        f32x4 o_[4][2] = {};
        #pragma unroll
        for (int ks = 0; ks < 2; ++ks) {
            bf16x8 bv0 = *(const bf16x8*)(vT + (h * 32 + lanelo) * VT_STRIDE + ks * 32 + quad * 8);
            bf16x8 bv1 = *(const bf16x8*)(vT + (h * 32 + 16 + lanelo) * VT_STRIDE + ks * 32 + quad * 8);
            #pragma unroll
            for (int mi = 0; mi < 4; ++mi) {
                const bf16x8 ap = *(const bf16x8*)(Pme + (mi * 16 + lanelo) * P_STRIDE + ks * 32 + quad * 8);
                o_[mi][0] = MFMA16(ap, bv0, o_[mi][0]);
                o_[mi][1] = MFMA16(ap, bv1, o_[mi][1]);
            }
        }
        #pragma unroll
        for (int mi = 0; mi < 4; ++mi)
            #pragma unroll
            for (int ni = 0; ni < 2; ++ni)
                #pragma unroll
                for (int r = 0; r < 4; ++r)
                    xao[(mi * 16 + quad * 4 + r) * XA_STRIDE + h * 32 + ni * 16 + lanelo] =
                        (bf16_t)o_[mi][ni][r];
    }
    __syncthreads();

    // ---- phase 3: proj GEMM + bias, scatter to output with inverse roll ----
    {
        #pragma unroll
        for (int ntl = 0; ntl < 2; ++ntl) {
            const int nt = wave * 2 + ntl;      // 12 N-tiles over 6 waves
            const int o  = nt * 16 + lanelo;    // output channel
            f32x4 acc[4] = {};
            #pragma unroll
            for (int ks = 0; ks < 6; ++ks) {
                const bf16x8 bfr = load_w8_bf16(proj_w + o * 192 + ks * 32 + quad * 8);
                #pragma unroll
                for (int mi = 0; mi < 4; ++mi) {
                    const bf16x8 afr = *(const bf16x8*)(xao + (mi * 16 + lanelo) * XA_STRIDE + ks * 32 + quad * 8);
                    acc[mi] = MFMA16(afr, bfr, acc[mi]);
                }
            }
            const float pbv = proj_b[o];
            #pragma unroll
            for (int mi = 0; mi < 4; ++mi) {
                #pragma unroll
                for (int r = 0; r < 4; ++r) {
                    const int row = mi * 16 + quad * 4 + r;
                    if (row < 49) {
                        int gr = rowbase + row / 7;  if (gr >= 112) gr -= 112;
                        int gc = colbase + row % 7;  if (gc >= 112) gc -= 112;
                        out[(((long)b * 112 + gr) * 112 + gc) * 192 + o] = acc[mi][r] + pbv;
                    }
                }
            }
        }
    }
}

extern "C" void kernel_launch(void* const* d_in, const int* in_sizes, int n_in,
                              void* d_out, int out_size, void* d_ws, size_t ws_size,
                              hipStream_t stream) {
    const float* x      = (const float*)d_in[0];
    const float* qkv_w  = (const float*)d_in[1];
    const float* qkv_b  = (const float*)d_in[2];
    const float* proj_w = (const float*)d_in[3];
    const float* proj_b = (const float*)d_in[4];
    const float* tbl    = (const float*)d_in[5];
    swin_fused_kernel<<<4096, 384, 0, stream>>>(x, qkv_w, qkv_b, proj_w, proj_b, tbl,
                                                (float*)d_out);
}

// Round 2
// 760.189 us; speedup vs baseline: 1.0302x; 1.0302x over previous
//
#include <hip/hip_runtime.h>

typedef __bf16 bf16_t;
typedef __bf16 bf16x8 __attribute__((ext_vector_type(8)));
typedef __bf16 bf16x4 __attribute__((ext_vector_type(4)));
typedef float  f32x4  __attribute__((ext_vector_type(4)));
typedef float  f32x8  __attribute__((ext_vector_type(8)));

#define MFMA16(a,b,c) __builtin_amdgcn_mfma_f32_16x16x32_bf16((a),(b),(c),0,0,0)

// LDS plan (bf16 elems), total 40182 -> 80,364 B -> 2 blocks/CU:
//   region [13056]: x [64][200]  ->(barrier)->  vT [192][68]  ->(barrier)-> attn [64][200]
//   scratch: per-wave [64][68] (Q roundtrip, K roundtrip, then P roundtrip)
//   bt [1014]: rel-bias table
#define REG_STRIDE 200
#define VT_STRIDE  68
#define SC_STRIDE  68
#define REG_ELEMS  13056
#define SC_ELEMS   (64 * SC_STRIDE)          // 4352
#define BT_OFF     (REG_ELEMS + 6 * SC_ELEMS)
#define SMEM_ELEMS (BT_OFF + 1014)           // 40182

__device__ __forceinline__ bf16x8 cvt8(const float4 a, const float4 b) {
    f32x8 v;
    v[0] = a.x; v[1] = a.y; v[2] = a.z; v[3] = a.w;
    v[4] = b.x; v[5] = b.y; v[6] = b.z; v[7] = b.w;
    return __builtin_convertvector(v, bf16x8);
}

// 64x32 GEMM over K=192: A-frags from LDS (row-major, REG_STRIDE), B-frags from
// global fp32 weight rows w0 (ni=0) / w1 (ni=1), prefetch depth 1.
__device__ __forceinline__ void gemm64x32(const bf16_t* __restrict__ xa,
                                          const float* __restrict__ w0,
                                          const float* __restrict__ w1,
                                          f32x4 acc[4][2]) {
    float4 pa = *(const float4*)(w0);
    float4 pb = *(const float4*)(w0 + 4);
    float4 pc = *(const float4*)(w1);
    float4 pd = *(const float4*)(w1 + 4);
    #pragma unroll
    for (int ks = 0; ks < 6; ++ks) {
        float4 na, nb, nc, nd;
        if (ks < 5) {
            na = *(const float4*)(w0 + (ks + 1) * 32);
            nb = *(const float4*)(w0 + (ks + 1) * 32 + 4);
            nc = *(const float4*)(w1 + (ks + 1) * 32);
            nd = *(const float4*)(w1 + (ks + 1) * 32 + 4);
        }
        const bf16x8 b0 = cvt8(pa, pb);
        const bf16x8 b1 = cvt8(pc, pd);
        #pragma unroll
        for (int mi = 0; mi < 4; ++mi) {
            const bf16x8 afr = *(const bf16x8*)(xa + (mi * 16) * REG_STRIDE + ks * 32);
            acc[mi][0] = MFMA16(afr, b0, acc[mi][0]);
            acc[mi][1] = MFMA16(afr, b1, acc[mi][1]);
        }
        pa = na; pb = nb; pc = nc; pd = nd;
    }
}

__global__ __launch_bounds__(384, 3)
void swin_fused_kernel(const float* __restrict__ x,
                       const float* __restrict__ qkv_w,
                       const float* __restrict__ qkv_b,
                       const float* __restrict__ proj_w,
                       const float* __restrict__ proj_b,
                       const float* __restrict__ tbl,
                       float* __restrict__ out)
{
    __shared__ __align__(16) bf16_t smem[SMEM_ELEMS];
    bf16_t* region = smem;
    bf16_t* bt     = smem + BT_OFF;

    const int tid    = threadIdx.x;
    const int lane   = tid & 63;
    const int wave   = tid >> 6;        // == head
    const int lanelo = lane & 15;
    const int quad   = lane >> 4;

    bf16_t* sc = smem + REG_ELEMS + wave * SC_ELEMS;   // per-wave scratch [64][68]

    const int blk = blockIdx.x;
    const int b   = blk >> 8;
    const int wh  = (blk >> 4) & 15;
    const int ww  = blk & 15;
    const int rowbase = wh * 7 + 3;     // shifted (i) -> orig (i+3)%112
    const int colbase = ww * 7 + 3;

    // ---- phase 0: bias table + x window -> LDS bf16 (rows 49..63 zeroed) ----
    for (int i = tid; i < 1014; i += 384) bt[i] = (bf16_t)tbl[i];

    for (int idx = tid; idx < 64 * 48; idx += 384) {
        const int t  = idx / 48;
        const int c4 = (idx - t * 48) * 4;
        bf16x4 v4;
        if (t < 49) {
            int gr = rowbase + t / 7;  if (gr >= 112) gr -= 112;
            int gc = colbase + t % 7;  if (gc >= 112) gc -= 112;
            const float4 f = *(const float4*)(x + (((long)b * 112 + gr) * 112 + gc) * 192 + c4);
            v4[0] = (bf16_t)f.x; v4[1] = (bf16_t)f.y;
            v4[2] = (bf16_t)f.z; v4[3] = (bf16_t)f.w;
        } else {
            v4[0] = (bf16_t)0.0f; v4[1] = (bf16_t)0.0f;
            v4[2] = (bf16_t)0.0f; v4[3] = (bf16_t)0.0f;
        }
        *(bf16x4*)(region + t * REG_STRIDE + c4) = v4;
    }
    __syncthreads();

    // ---- phase 1: per-wave head QKV (each wave computes its own head slice) ----
    const int h = wave;
    const bf16_t* xa = region + lanelo * REG_STRIDE + quad * 8;

    bf16x8 qa[4], kb[4];
    f32x4  vacc[4][2];
    {
        // Q
        {
            const float* wb = qkv_w + (0 * 192 + h * 32) * 192;
            f32x4 acc[4][2] = {};
            gemm64x32(xa, wb + lanelo * 192 + quad * 8, wb + (16 + lanelo) * 192 + quad * 8, acc);
            const float bias0 = qkv_b[0 * 192 + h * 32 + lanelo];
            const float bias1 = qkv_b[0 * 192 + h * 32 + 16 + lanelo];
            #pragma unroll
            for (int mi = 0; mi < 4; ++mi)
                #pragma unroll
                for (int r = 0; r < 4; ++r) {
                    const int row = quad * 4 + r + 16 * mi;
                    sc[row * SC_STRIDE + lanelo]      = (bf16_t)(acc[mi][0][r] + bias0);
                    sc[row * SC_STRIDE + 16 + lanelo] = (bf16_t)(acc[mi][1][r] + bias1);
                }
            #pragma unroll
            for (int mi = 0; mi < 4; ++mi)
                qa[mi] = *(const bf16x8*)(sc + (lanelo + 16 * mi) * SC_STRIDE + quad * 8);
        }
        // K
        {
            const float* wb = qkv_w + (1 * 192 + h * 32) * 192;
            f32x4 acc[4][2] = {};
            gemm64x32(xa, wb + lanelo * 192 + quad * 8, wb + (16 + lanelo) * 192 + quad * 8, acc);
            const float bias0 = qkv_b[1 * 192 + h * 32 + lanelo];
            const float bias1 = qkv_b[1 * 192 + h * 32 + 16 + lanelo];
            #pragma unroll
            for (int mi = 0; mi < 4; ++mi)
                #pragma unroll
                for (int r = 0; r < 4; ++r) {
                    const int row = quad * 4 + r + 16 * mi;
                    sc[row * SC_STRIDE + lanelo]      = (bf16_t)(acc[mi][0][r] + bias0);
                    sc[row * SC_STRIDE + 16 + lanelo] = (bf16_t)(acc[mi][1][r] + bias1);
                }
            #pragma unroll
            for (int mi = 0; mi < 4; ++mi)
                kb[mi] = *(const bf16x8*)(sc + (lanelo + 16 * mi) * SC_STRIDE + quad * 8);
        }
        // V (keep acc in regs; written to vT after the barrier)
        {
            const float* wb = qkv_w + (2 * 192 + h * 32) * 192;
            f32x4 acc[4][2] = {};
            gemm64x32(xa, wb + lanelo * 192 + quad * 8, wb + (16 + lanelo) * 192 + quad * 8, acc);
            #pragma unroll
            for (int mi = 0; mi < 4; ++mi) {
                vacc[mi][0] = acc[mi][0];
                vacc[mi][1] = acc[mi][1];
            }
        }
    }
    __syncthreads();   // all x reads done -> region becomes vT

    // vT write: region[dim][token], stride 68; wave h owns dims h*32..h*32+31
    {
        const float bias0 = qkv_b[2 * 192 + h * 32 + lanelo];
        const float bias1 = qkv_b[2 * 192 + h * 32 + 16 + lanelo];
        #pragma unroll
        for (int mi = 0; mi < 4; ++mi)
            #pragma unroll
            for (int r = 0; r < 4; ++r) {
                const int tok = quad * 4 + r + 16 * mi;
                region[(h * 32 + lanelo) * VT_STRIDE + tok]      = (bf16_t)(vacc[mi][0][r] + bias0);
                region[(h * 32 + 16 + lanelo) * VT_STRIDE + tok] = (bf16_t)(vacc[mi][1][r] + bias1);
            }
    }

    // ---- phase 2: S = Q K^T, mask+softmax (per-mi), P roundtrip, PV ----
    f32x4 o_[4][2] = {};
    {
        const float scale = 0.17677669529663687f;   // 32^-0.5

        // per-lane key-column attributes for each ni tile
        int kvalid[4], kch[4], kcw[4], kid[4];
        #pragma unroll
        for (int ni = 0; ni < 4; ++ni) {
            const int col = ni * 16 + lanelo;
            kvalid[ni] = (col < 49);
            const int cc = kvalid[ni] ? col : 48;
            kch[ni] = cc / 7; kcw[ni] = cc - kch[ni] * 7;
            const int gr = wh * 7 + kch[ni], gc = ww * 7 + kcw[ni];
            kid[ni] = (gr < 105 ? 0 : (gr < 109 ? 1 : 2)) * 3 + (gc < 105 ? 0 : (gc < 109 ? 1 : 2));
        }

        #pragma unroll
        for (int mi = 0; mi < 4; ++mi) {
            f32x4 s[4];
            #pragma unroll
            for (int ni = 0; ni < 4; ++ni) {
                f32x4 z = {0.f, 0.f, 0.f, 0.f};
                s[ni] = MFMA16(qa[mi], kb[ni], z);
            }
            #pragma unroll
            for (int r = 0; r < 4; ++r) {
                const int row = mi * 16 + quad * 4 + r;
                const int rq  = (row < 49) ? row : 48;
                const int rh  = rq / 7, rw = rq - (rq / 7) * 7;
                const int gqr = wh * 7 + rh, gqc = ww * 7 + rw;
                const int idq = (gqr < 105 ? 0 : (gqr < 109 ? 1 : 2)) * 3 + (gqc < 105 ? 0 : (gqc < 109 ? 1 : 2));
                #pragma unroll
                for (int ni = 0; ni < 4; ++ni) {
                    float v;
                    if (kvalid[ni]) {
                        const int bidx = ((rh - kch[ni] + 6) * 13 + (rw - kcw[ni] + 6)) * 6 + h;
                        v = s[ni][r] * scale + (float)bt[bidx];
                        if (idq != kid[ni]) v -= 100.0f;
                    } else {
                        v = -1e30f;
                    }
                    s[ni][r] = v;
                }
                float m0 = fmaxf(fmaxf(s[0][r], s[1][r]), fmaxf(s[2][r], s[3][r]));
                m0 = fmaxf(m0, __shfl_xor(m0, 1));
                m0 = fmaxf(m0, __shfl_xor(m0, 2));
                m0 = fmaxf(m0, __shfl_xor(m0, 4));
                m0 = fmaxf(m0, __shfl_xor(m0, 8));
                float sum = 0.f;
                #pragma unroll
                for (int ni = 0; ni < 4; ++ni) {
                    const float e = __expf(s[ni][r] - m0);
                    s[ni][r] = e;
                    sum += e;
                }
                sum += __shfl_xor(sum, 1);
                sum += __shfl_xor(sum, 2);
                sum += __shfl_xor(sum, 4);
                sum += __shfl_xor(sum, 8);
                const float rinv = 1.0f / sum;
                #pragma unroll
                for (int ni = 0; ni < 4; ++ni)
                    sc[row * SC_STRIDE + ni * 16 + lanelo] = (bf16_t)(s[ni][r] * rinv);
            }
        }

        // PV: A = P (scratch roundtrip), B = vT (own head rows of region)
        #pragma unroll
        for (int ks = 0; ks < 2; ++ks) {
            const bf16x8 bv0 = *(const bf16x8*)(region + (h * 32 + lanelo) * VT_STRIDE + ks * 32 + quad * 8);
            const bf16x8 bv1 = *(const bf16x8*)(region + (h * 32 + 16 + lanelo) * VT_STRIDE + ks * 32 + quad * 8);
            #pragma unroll
            for (int mi = 0; mi < 4; ++mi) {
                const bf16x8 ap = *(const bf16x8*)(sc + (lanelo + 16 * mi) * SC_STRIDE + ks * 32 + quad * 8);
                o_[mi][0] = MFMA16(ap, bv0, o_[mi][0]);
                o_[mi][1] = MFMA16(ap, bv1, o_[mi][1]);
            }
        }
    }
    __syncthreads();   // all vT reads done -> region becomes attn_out

    // attn_out write (C-layout), rows = tokens, stride 200
    #pragma unroll
    for (int mi = 0; mi < 4; ++mi)
        #pragma unroll
        for (int r = 0; r < 4; ++r) {
            const int row = quad * 4 + r + 16 * mi;
            region[row * REG_STRIDE + h * 32 + lanelo]      = (bf16_t)(o_[mi][0][r]);
            region[row * REG_STRIDE + h * 32 + 16 + lanelo] = (bf16_t)(o_[mi][1][r]);
        }
    __syncthreads();

    // ---- phase 3: proj GEMM + bias, scatter to output with inverse roll ----
    {
        const float* wb = proj_w + (wave * 32) * 192;
        f32x4 acc[4][2] = {};
        gemm64x32(xa, wb + lanelo * 192 + quad * 8, wb + (16 + lanelo) * 192 + quad * 8, acc);
        const int o0 = wave * 32 + lanelo;
        const int o1 = wave * 32 + 16 + lanelo;
        const float pb0 = proj_b[o0];
        const float pb1 = proj_b[o1];
        #pragma unroll
        for (int mi = 0; mi < 4; ++mi)
            #pragma unroll
            for (int r = 0; r < 4; ++r) {
                const int row = quad * 4 + r + 16 * mi;
                if (row < 49) {
                    int gr = rowbase + row / 7;  if (gr >= 112) gr -= 112;
                    int gc = colbase + row % 7;  if (gc >= 112) gc -= 112;
                    float* op = out + (((long)b * 112 + gr) * 112 + gc) * 192;
                    op[o0] = acc[mi][0][r] + pb0;
                    op[o1] = acc[mi][1][r] + pb1;
                }
            }
    }
}

extern "C" void kernel_launch(void* const* d_in, const int* in_sizes, int n_in,
                              void* d_out, int out_size, void* d_ws, size_t ws_size,
                              hipStream_t stream) {
    const float* x      = (const float*)d_in[0];
    const float* qkv_w  = (const float*)d_in[1];
    const float* qkv_b  = (const float*)d_in[2];
    const float* proj_w = (const float*)d_in[3];
    const float* proj_b = (const float*)d_in[4];
    const float* tbl    = (const float*)d_in[5];
    swin_fused_kernel<<<4096, 384, 0, stream>>>(x, qkv_w, qkv_b, proj_w, proj_b, tbl,
                                                (float*)d_out);
}